// Round 8
// baseline (220.794 us; speedup 1.0000x reference)
//
#include <hip/hip_runtime.h>
#include <hip/hip_fp8.h>
#include <math.h>
#include <utility>

// N = 100000 nodes, SEQ = 16, layers: 3 ->16 ->32 ->64 ->128 ->256 ->12(log_softmax)
// R25 (bank green + safe wins):
//   R24 (TILE128 mfma3) failed stale-LDS like R19/R21/R23. Root-cause theory:
//   register spills insert scratch buffer ops that INCREMENT VMCNT, corrupting all
//   hand-counted s_waitcnt. Only lean configs (VGPR 56-76) ever passed. Rule: the
//   manual-vmcnt loop only runs in proven lean configs -- mfma3 reverted to the
//   R20/R22-green TILE64 depth-2 kernel (green twice).
//   Safe changes (no vmcnt accounting touched):
//   - fc12: 64 rows/block (t-loop over two 32-row halves, weights loaded once).
//     Halves ~250MB of per-block fc1/fc2 weight re-reads. Standard syncthreads.
//   - prep fusion: cvt_swz + idxT + fc0 in ONE kernel (blockIdx-range branch) ->
//     2 fewer launches.
// spiral1/2: R22-green hardened depth-2 mfma_layer (unchanged).
// R18 kept: HW OCP-fp8 cvt, LDS chunk swizzle f(r)=(r&3)^((r>>2)&3).

typedef __bf16 bf16x8 __attribute__((ext_vector_type(8)));
typedef float f32x16 __attribute__((ext_vector_type(16)));
typedef float f32x2 __attribute__((ext_vector_type(2)));

template <int V> using ic = std::integral_constant<int, V>;

template <typename F, int... Is>
__device__ __forceinline__ void static_for_impl(F&& f, std::integer_sequence<int, Is...>) {
    (f(ic<Is>{}), ...);
}
template <int N_, typename F>
__device__ __forceinline__ void static_for(F&& f) {
    static_for_impl(static_cast<F&&>(f), std::make_integer_sequence<int, N_>{});
}

template <int N_>
__device__ __forceinline__ void wait_vmcnt() {
    static_assert(N_ <= 63, "vmcnt range");
    __builtin_amdgcn_s_waitcnt((N_ & 0xF) | (0x7 << 4) | (0xF << 8) | ((N_ >> 4) << 14));
}

__device__ __forceinline__ void memfence_sched() { __builtin_amdgcn_sched_barrier(0x000F); }

__device__ __forceinline__ float elu_f(float v) { return v > 0.f ? v : expm1f(v); }

// HW encode: f32 -> OCP e4m3 (RNE, satfinite) via v_cvt_pk_fp8_f32, take byte 0.
__device__ __forceinline__ unsigned char to_fp8(float v) {
    int p = __builtin_amdgcn_cvt_pk_fp8_f32(v, v, 0, false);
    return (unsigned char)p;
}

__device__ __forceinline__ unsigned int pk_bf16(float a, float b) {
    unsigned int r;
    asm("v_cvt_pk_bf16_f32 %0, %1, %2" : "=v"(r) : "v"(a), "v"(b));
    return r;
}

// 8 packed fp8 e4m3 -> bf16x8, fully hardware: 4x v_cvt_pk_f32_fp8 + 4x v_cvt_pk_bf16_f32.
// Exact: every e4m3 value (incl. denormals) is representable in bf16.
__device__ __forceinline__ bf16x8 dq8(long v) {
    unsigned int lo = (unsigned int)(unsigned long)v;
    unsigned int hi = (unsigned int)((unsigned long)v >> 32);
    f32x2 f0 = __builtin_amdgcn_cvt_pk_f32_fp8((int)lo, false);
    f32x2 f1 = __builtin_amdgcn_cvt_pk_f32_fp8((int)lo, true);
    f32x2 f2 = __builtin_amdgcn_cvt_pk_f32_fp8((int)hi, false);
    f32x2 f3 = __builtin_amdgcn_cvt_pk_f32_fp8((int)hi, true);
    union { unsigned int u[4]; bf16x8 b; } r;
    r.u[0] = pk_bf16(f0[0], f0[1]);
    r.u[1] = pk_bf16(f1[0], f1[1]);
    r.u[2] = pk_bf16(f2[0], f2[1]);
    r.u[3] = pk_bf16(f3[0], f3[1]);
    return r.b;
}

// ------------------------------------------------ weight prep (all bf16 frag-major)
// dst chunk ((k/64)*8 + (k%64)/8)*C + col, elem k%8  <- src[col*K+k]
template <int K, int C>
__device__ __forceinline__ void swz_one(const float* __restrict__ src, __bf16* __restrict__ dst, int j)
{
    int col = j / K;
    int k = j & (K - 1);
    int chunk = ((k >> 6) * 8 + ((k & 63) >> 3)) * C + col;
    dst[chunk * 8 + (k & 7)] = (__bf16)src[j];
}

// ------------------------------------------------ FUSED prep: cvt_swz + idxT + fc0
// blocks [0,832): weight swizzle; [832,7082): idx transpose; [7082,7473): fc0.
__global__ __launch_bounds__(256) void prep_kernel(const float* __restrict__ w1,
                                                   const float* __restrict__ w2,
                                                   const float* __restrict__ w3,
                                                   const float* __restrict__ f1,
                                                   const float* __restrict__ f2,
                                                   __bf16* __restrict__ d1,
                                                   __bf16* __restrict__ d2,
                                                   __bf16* __restrict__ d3,
                                                   __bf16* __restrict__ df1,
                                                   __bf16* __restrict__ df2p,
                                                   const int* __restrict__ idx,
                                                   int* __restrict__ idxT,
                                                   const float* __restrict__ x,
                                                   const float* __restrict__ fc0_w,
                                                   const float* __restrict__ fc0_b,
                                                   __bf16* __restrict__ h0,
                                                   int N)
{
    int b = blockIdx.x;
    if (b < 832) {
        int i = b * 256 + threadIdx.x;   // < 212992
        if (i < 8192)        swz_one<256, 32>(w1, d1, i);
        else if (i < 40960)  swz_one<512, 64>(w2, d2, i - 8192);
        else if (i < 172032) swz_one<1024, 128>(w3, d3, i - 40960);
        else if (i < 204800) swz_one<128, 256>(f1, df1, i - 172032);
        else {
            // fc2 padded to 32 cols, frag-major (K=256, C=32); inverse map over DEST index
            int d = i - 204800;
            int e = d & 7;
            int chunkIdx = d >> 3;
            int col = chunkIdx & 31;
            int q = chunkIdx >> 5;
            int k = (q >> 3) * 64 + (q & 7) * 8 + e;
            df2p[d] = (col < 12) ? (__bf16)f2[col * 256 + k] : (__bf16)0.f;
        }
    } else if (b < 7082) {
        int i = (b - 832) * 256 + threadIdx.x;
        if (i < N * 16) {
            int n = i >> 4, s = i & 15;
            idxT[s * N + n] = idx[i];
        }
    } else {
        int n = (b - 7082) * 256 + threadIdx.x;
        if (n < N) {
            float x0 = x[n * 3 + 0], x1 = x[n * 3 + 1], x2 = x[n * 3 + 2];
            __bf16 ob[16];
#pragma unroll
            for (int j = 0; j < 16; ++j)
                ob[j] = (__bf16)elu_f(fc0_w[j * 3 + 0] * x0 + fc0_w[j * 3 + 1] * x1
                                      + fc0_w[j * 3 + 2] * x2 + fc0_b[j]);
            int4* dst = (int4*)&h0[(size_t)n * 16];
            dst[0] = *(int4*)&ob[0];
            dst[1] = *(int4*)&ob[8];
        }
    }
}

// ------------------------------------------- depth-2 wait-at-top bf16 MFMA gather-GEMM (R22)
// Hardened wait: NW = D*(s+1<NSTEP) + I*(s+3<NSTEP) counts ONLY the youngest two
// vmem groups -> always <= true outstanding-after-DMA(s) -> DMA(s) complete by
// in-order vmcnt retirement. DMA(s+1) prefetch stays in flight across the wait.
// OUTF8: epilogue emits fp8 e4m3 instead of bf16 (used by spiral2 -> h2).
template <int CIN, int S, int COUT_B, int COUT_TOT, int TILE_M, int RW, int CW,
          bool GATHER, bool OUTF8, int MINW, int NN>
__global__ __launch_bounds__(256, MINW) void mfma_layer(const __bf16* __restrict__ hin,
                                                        const int* __restrict__ idxT,
                                                        const __bf16* __restrict__ Wsw,
                                                        const float* __restrict__ bias,
                                                        void* __restrict__ hout)
{
    constexpr int K = CIN * S;
    constexpr int NSTEP = K / 64;
    static_assert(K % 64 == 0, "K%64");
    constexpr int WM = TILE_M / RW;
    constexpr int WN = COUT_B / CW;
    constexpr int MT = WM / 32;
    constexpr int NT = WN / 32;
    constexpr int IPS = GATHER ? (64 / CIN) : 1;
    constexpr int D = WM / 8;
    constexpr int Bn = NT * 4;
    constexpr int I = GATHER ? D : 0;
    constexpr int NBUFS = 3;
    static_assert(RW * CW == 4, "4 waves");
    static_assert(WM == 32 || WM == 64, "1-2 row subtiles per wave");

    constexpr int AB = 4 * NBUFS * WM * 128;
    constexpr int CB = OUTF8 ? TILE_M * (COUT_B + 16) : TILE_M * (COUT_B + 8) * 2;
    constexpr int SH = AB > CB ? AB : CB;
    __shared__ __align__(16) char smem[SH];

    const int tid = threadIdx.x;
    const int lane = tid & 63;
    const int w = tid >> 6;
    const int wr = w / CW;
    const int wc = w % CW;
    const int ml = lane & 31;
    const int kh = lane >> 5;
    const int m0 = blockIdx.x * TILE_M;
    const int col0 = blockIdx.y * COUT_B;
    const int rbase = m0 + wr * WM;

    char* const Aw = smem + w * (NBUFS * WM * 128);

    int ioff[GATHER ? D : 1];
    int koff[GATHER ? D : 1];
    int gmr[GATHER ? 1 : D];
    int coff[GATHER ? 1 : D];
#pragma unroll
    for (int i = 0; i < D; ++i) {
        int r = i * 8 + (lane >> 3);
        int c = (lane & 7) ^ (r & 7);
        int gm = rbase + r; if (gm >= NN) gm = NN - 1;
        if constexpr (GATHER) {
            ioff[i] = ((c * 8) / CIN) * NN + gm;
            koff[i] = (c * 8) & (CIN - 1);
        } else {
            gmr[i] = gm;
            coff[i] = c * 8;
        }
    }

    bf16x8 bfr[2][NT][4];
    int myIdx[GATHER ? 3 : 1][GATHER ? D : 1];

    const __bf16* wlane = Wsw + ((size_t)(col0 + wc * WN + ml) + (size_t)kh * COUT_TOT) * 8;

    auto loadB = [&](auto sc) {
        constexpr int s = decltype(sc)::value;
        if constexpr (s < NSTEP) {
#pragma unroll
            for (int ni = 0; ni < NT; ++ni)
#pragma unroll
                for (int ks = 0; ks < 4; ++ks)
                    bfr[s & 1][ni][ks] = *(const bf16x8*)(wlane
                        + (size_t)(s * 8 + ks * 2) * COUT_TOT * 8 + ni * 32 * 8);
        }
    };
    auto loadIdxS = [&](auto sc) {
        constexpr int s = decltype(sc)::value;
        if constexpr (GATHER && s < NSTEP) {
#pragma unroll
            for (int i = 0; i < D; ++i)
                myIdx[s % 3][i] = idxT[(s * IPS) * NN + ioff[i]];
        }
    };
    auto issueDMA = [&](auto sc) {
        constexpr int s = decltype(sc)::value;
        if constexpr (s < NSTEP) {
            char* base = Aw + (s % NBUFS) * (WM * 128);
#pragma unroll
            for (int i = 0; i < D; ++i) {
                const __bf16* src;
                if constexpr (GATHER)
                    src = hin + (size_t)myIdx[s % 3][i] * CIN + koff[i];
                else
                    src = hin + (size_t)gmr[i] * K + s * 64 + coff[i];
                __builtin_amdgcn_global_load_lds(
                    (const __attribute__((address_space(1))) void*)src,
                    (__attribute__((address_space(3))) void*)(base + i * 1024),
                    16, 0, 0);
            }
        }
    };

    f32x16 acc[MT][NT];
#pragma unroll
    for (int mi = 0; mi < MT; ++mi)
#pragma unroll
        for (int ni = 0; ni < NT; ++ni) { f32x16 z = {}; acc[mi][ni] = z; }

    // depth-2 prologue: idx0..2, B0, DMA0, DMA1, idx3
    loadIdxS(ic<0>{});
    loadIdxS(ic<1>{});
    loadIdxS(ic<2>{});
    memfence_sched();
    loadB(ic<0>{});
    memfence_sched();
    issueDMA(ic<0>{});
    memfence_sched();
    issueDMA(ic<1>{});
    memfence_sched();
    loadIdxS(ic<3>{});
    memfence_sched();

    static_for<NSTEP>([&](auto sc) {
        constexpr int s = decltype(sc)::value;
        // HARDENED wait-at-top: count only DMA(s+1) + idx(s+3), the youngest groups.
        constexpr int NW = D * (s + 1 < NSTEP) + I * (s + 3 < NSTEP);
        wait_vmcnt<NW>();
        memfence_sched();

        // ds_read A fragments (pinned between fences)
        const char* base = Aw + (s % NBUFS) * (WM * 128);
        bf16x8 afr[MT][4];
#pragma unroll
        for (int mi = 0; mi < MT; ++mi)
#pragma unroll
            for (int ks = 0; ks < 4; ++ks) {
                int cb = ks * 2 + kh;
                afr[mi][ks] = *(const bf16x8*)(base + ((mi * 32 + ml) * 8 + (cb ^ (ml & 7))) * 16);
            }
        memfence_sched();

        // issue next-iteration vmem while this iteration computes
        loadB(ic<s + 1>{});
        memfence_sched();
        issueDMA(ic<s + 2>{});
        memfence_sched();
        loadIdxS(ic<s + 4>{});
        memfence_sched();

#pragma unroll
        for (int ks = 0; ks < 4; ++ks)
#pragma unroll
            for (int mi = 0; mi < MT; ++mi)
#pragma unroll
                for (int ni = 0; ni < NT; ++ni)
                    acc[mi][ni] = __builtin_amdgcn_mfma_f32_32x32x16_bf16(
                        afr[mi][ks], bfr[s & 1][ni][ks], acc[mi][ni], 0, 0, 0);
    });

    // ---- epilogue
    __syncthreads();
    if constexpr (OUTF8) {
        unsigned char* Cs8 = (unsigned char*)smem;
        constexpr int LDC8 = COUT_B + 16;
#pragma unroll
        for (int ni = 0; ni < NT; ++ni) {
            const int col = wc * WN + ni * 32 + ml;
            const float bv = bias[col0 + col];
#pragma unroll
            for (int mi = 0; mi < MT; ++mi) {
#pragma unroll
                for (int r = 0; r < 16; ++r) {
                    int row = wr * WM + mi * 32 + ((r & 3) + 8 * (r >> 2) + 4 * kh);
                    Cs8[row * LDC8 + col] = to_fp8(elu_f(acc[mi][ni][r] + bv));
                }
            }
        }
        __syncthreads();
        constexpr int C16 = COUT_B / 16;
#pragma unroll
        for (int j2 = tid; j2 < TILE_M * C16; j2 += 256) {
            int row = j2 / C16, c16 = j2 % C16;
            int gm = m0 + row;
            if (gm < NN)
                *(int4*)((unsigned char*)hout + (size_t)gm * COUT_TOT + col0 + c16 * 16)
                    = *(int4*)&Cs8[row * LDC8 + c16 * 16];
        }
    } else {
        __bf16* Cs = (__bf16*)smem;
        constexpr int LDC = COUT_B + 8;
#pragma unroll
        for (int ni = 0; ni < NT; ++ni) {
            const int col = wc * WN + ni * 32 + ml;
            const float bv = bias[col0 + col];
#pragma unroll
            for (int mi = 0; mi < MT; ++mi) {
#pragma unroll
                for (int r = 0; r < 16; ++r) {
                    int row = wr * WM + mi * 32 + ((r & 3) + 8 * (r >> 2) + 4 * kh);
                    Cs[row * LDC + col] = (__bf16)elu_f(acc[mi][ni][r] + bv);
                }
            }
        }
        __syncthreads();
        constexpr int C8 = COUT_B / 8;
#pragma unroll
        for (int j2 = tid; j2 < TILE_M * C8; j2 += 256) {
            int row = j2 / C8, c8 = j2 % C8;
            int gm = m0 + row;
            if (gm < NN)
                *(int4*)&((__bf16*)hout)[(size_t)gm * COUT_TOT + col0 + c8 * 8] = *(int4*)&Cs[row * LDC + c8 * 8];
        }
    }
}

// ------------------------------------------- spiral3 MIXED: fp8 h2 gather + bf16 MFMA
// EXACT R20/R22-GREEN KERNEL (green twice; do not touch): TILE 64 (RW=2, CW=2),
// wave 32x64, K=1024, NSTEP=16, depth-2 DMA (NBUFS=3), WAIT-AT-TOP, R20 NW formula.
// A: ds_read_b64 fp8 -> HW dequant to bf16x8. B: bf16 frag-major w3 (exact).
// Chunk swizzle f(r) = (r&3)^((r>>2)&3): ds_read_b64 conflicts 8-way -> 4-way (floor).
__global__ __launch_bounds__(256, 3) void mfma3_mixed(const unsigned char* __restrict__ h2f8, // [N,64] e4m3
                                                      const int* __restrict__ idxT,
                                                      const __bf16* __restrict__ Wsw,         // bf16 frag-major (K=1024,C=128)
                                                      const float* __restrict__ bias,
                                                      __bf16* __restrict__ h3)
{
    constexpr int NN = 100000;
    constexpr int NSTEP = 16;
    constexpr int D = 2;        // DMA insts per step per wave (32 rows x 64 B)
    constexpr int Bn = 8;       // B vmem loads per step
    constexpr int I = 2;        // idx loads per step
    constexpr int NBUFS = 3;
    __shared__ __align__(16) char smem[24576];   // A: 4 waves x 3 bufs x 2KB; epilogue 64x136 bf16 = 17408

    const int tid = threadIdx.x;
    const int lane = tid & 63;
    const int w = tid >> 6;
    const int wr = w >> 1;
    const int wc = w & 1;
    const int ml = lane & 31;
    const int kh = lane >> 5;
    const int m0 = blockIdx.x * 64;
    const int rbase = m0 + wr * 32;

    char* const Aw = smem + w * (NBUFS * 2048);

    // DMA geometry: inst i, lane t -> row r=i*16+(t>>2), phys chunk t&3 holds src chunk
    // (t&3) ^ (r&3) ^ ((r>>2)&3)
    int ioff[D], koff[D];
#pragma unroll
    for (int i = 0; i < D; ++i) {
        int r = i * 16 + (lane >> 2);
        int c = (lane & 3) ^ (r & 3) ^ ((r >> 2) & 3);
        int gm = rbase + r; if (gm >= NN) gm = NN - 1;
        ioff[i] = gm;
        koff[i] = c * 16;
    }

    bf16x8 bfr[2][2][4];
    int myIdx[3][D];

    const __bf16* wlane = Wsw + ((size_t)(wc * 64 + ml) + (size_t)kh * 128) * 8;

    auto loadB = [&](auto sc) {
        constexpr int s = decltype(sc)::value;
        if constexpr (s < NSTEP) {
#pragma unroll
            for (int ni = 0; ni < 2; ++ni)
#pragma unroll
                for (int ks = 0; ks < 4; ++ks)
                    bfr[s & 1][ni][ks] = *(const bf16x8*)(wlane
                        + (size_t)(s * 8 + ks * 2) * 128 * 8 + ni * 32 * 8);
        }
    };
    auto loadIdxS = [&](auto sc) {
        constexpr int s = decltype(sc)::value;
        if constexpr (s < NSTEP) {
#pragma unroll
            for (int i = 0; i < D; ++i)
                myIdx[s % 3][i] = idxT[(size_t)s * NN + ioff[i]];
        }
    };
    auto issueDMA = [&](auto sc) {
        constexpr int s = decltype(sc)::value;
        if constexpr (s < NSTEP) {
            char* base = Aw + (s % NBUFS) * 2048;
#pragma unroll
            for (int i = 0; i < D; ++i) {
                const unsigned char* src = h2f8 + (size_t)myIdx[s % 3][i] * 64 + koff[i];
                __builtin_amdgcn_global_load_lds(
                    (const __attribute__((address_space(1))) void*)src,
                    (__attribute__((address_space(3))) void*)(base + i * 1024),
                    16, 0, 0);
            }
        }
    };

    f32x16 acc[2];
    { f32x16 z = {}; acc[0] = z; acc[1] = z; }

    // depth-2 prologue: idx0..2, B0, DMA0, DMA1, idx3
    loadIdxS(ic<0>{});
    loadIdxS(ic<1>{});
    loadIdxS(ic<2>{});
    memfence_sched();
    loadB(ic<0>{});
    memfence_sched();
    issueDMA(ic<0>{});
    memfence_sched();
    issueDMA(ic<1>{});
    memfence_sched();
    loadIdxS(ic<3>{});
    memfence_sched();

    static_for<NSTEP>([&](auto sc) {
        constexpr int s = decltype(sc)::value;
        // wait for DMA(s) at iteration TOP. Ops issued after DMA(s):
        //  s==0 (prologue): DMA(1)=D, idx(3)=I.
        //  s>=1: idx(s+2) [iter s-2] + B(s) [iter s-1, always] + DMA(s+1) + idx(s+3).
        constexpr int NW = (s == 0)
            ? (D * (1 < NSTEP) + I * (3 < NSTEP))
            : (I * (s + 2 < NSTEP) + Bn + D * (s + 1 < NSTEP) + I * (s + 3 < NSTEP));
        wait_vmcnt<NW>();
        memfence_sched();

        // ds_read raw fp8 rows (pinned between fences: cannot move above the wait)
        const char* base = Aw + (s % NBUFS) * 2048;
        long a8[4];
#pragma unroll
        for (int ks = 0; ks < 4; ++ks)
            a8[ks] = *(const long*)(base + ml * 64
                + (((ks ^ (ml & 3)) ^ ((ml >> 2) & 3)) << 4) + kh * 8);
        memfence_sched();

        // issue next-iteration vmem while this iteration computes
        loadB(ic<s + 1>{});
        memfence_sched();
        issueDMA(ic<s + 2>{});
        memfence_sched();
        loadIdxS(ic<s + 4>{});
        memfence_sched();

        bf16x8 afr[4];
#pragma unroll
        for (int ks = 0; ks < 4; ++ks)
            afr[ks] = dq8(a8[ks]);   // HW fp8 e4m3 -> bf16 (exact)
#pragma unroll
        for (int ks = 0; ks < 4; ++ks)
#pragma unroll
            for (int ni = 0; ni < 2; ++ni)
                acc[ni] = __builtin_amdgcn_mfma_f32_32x32x16_bf16(
                    afr[ks], bfr[s & 1][ni][ks], acc[ni], 0, 0, 0);
    });

    // ---- epilogue: bf16 h3, coalesced
    __syncthreads();
    __bf16* Cs = (__bf16*)smem;
#pragma unroll
    for (int ni = 0; ni < 2; ++ni) {
        const int col = wc * 64 + ni * 32 + ml;
        const float bv = bias[col];
#pragma unroll
        for (int r = 0; r < 16; ++r) {
            int row = wr * 32 + ((r & 3) + 8 * (r >> 2) + 4 * kh);
            Cs[row * 136 + col] = (__bf16)elu_f(acc[ni][r] + bv);
        }
    }
    __syncthreads();
#pragma unroll
    for (int j2 = tid; j2 < 64 * 16; j2 += 256) {
        int row = j2 >> 4, c8 = j2 & 15;
        int gm = m0 + row;
        if (gm < NN)
            *(int4*)&h3[(size_t)gm * 128 + c8 * 8] = *(int4*)&Cs[row * 136 + c8 * 8];
    }
}

// ------------------------------------------- FUSED fc1 + fc2(MFMA) + log_softmax
// R25: 64 rows/block -- weights (fc1 frag-major + fc2 padded) loaded ONCE into
// registers, then the R15-proven 32-row body runs twice. Standard syncthreads only.
__global__ __launch_bounds__(256, 3) void fc12_kernel(const __bf16* __restrict__ h3,   // [N,128]
                                                      const __bf16* __restrict__ Wsw,  // fc1 frag-major (K=128,C=256)
                                                      const float* __restrict__ bias1,
                                                      const __bf16* __restrict__ W2p,  // fc2 frag-major padded (K=256,C=32)
                                                      const float* __restrict__ bias2,
                                                      float* __restrict__ out,
                                                      int N)
{
    __shared__ __align__(16) char smem[32 * 264 * 2];
    const int tid = threadIdx.x;
    const int lane = tid & 63;
    const int w = tid >> 6;
    const int ml = lane & 31;
    const int kh = lane >> 5;
    const int m0 = blockIdx.x * 64;

    const __bf16* wlane = Wsw + ((size_t)(w * 64 + ml) + (size_t)kh * 256) * 8;
    bf16x8 bfr[2][2][4];
#pragma unroll
    for (int s = 0; s < 2; ++s)
#pragma unroll
        for (int ni = 0; ni < 2; ++ni)
#pragma unroll
            for (int ks = 0; ks < 4; ++ks)
                bfr[s][ni][ks] = *(const bf16x8*)(wlane
                    + (size_t)(s * 8 + ks * 2) * 256 * 8 + ni * 32 * 8);

    bf16x8 b2f[4];
#pragma unroll
    for (int ks = 0; ks < 4; ++ks)
        b2f[ks] = *(const bf16x8*)&W2p[((w * 8 + ks * 2 + kh) * 32 + ml) * 8];

#pragma unroll
    for (int half = 0; half < 2; ++half) {
        const int mb = m0 + half * 32;
        if (mb >= N) break;              // block-uniform guard (N % 32 == 0)
        if (half) __syncthreads();       // protect smem from previous half's readers

#pragma unroll
        for (int t = 0; t < 2; ++t) {
            int j = w * 2 + t;
            int lr = j * 4 + (lane >> 4);
            int sc = (lane & 15) ^ (lr & 15);
            const __bf16* src = h3 + (size_t)(mb + lr) * 128 + sc * 8;
            __builtin_amdgcn_global_load_lds(
                (const __attribute__((address_space(1))) void*)src,
                (__attribute__((address_space(3))) void*)(smem + j * 1024),
                16, 0, 0);
        }
        wait_vmcnt<0>();
        __syncthreads();

        f32x16 acc[2];
        { f32x16 z = {}; acc[0] = z; acc[1] = z; }
        const char* Ab = smem;
#pragma unroll
        for (int s = 0; s < 2; ++s) {
            bf16x8 afr[4];
#pragma unroll
            for (int ks = 0; ks < 4; ++ks) {
                int c16 = s * 8 + ks * 2 + kh;
                afr[ks] = *(const bf16x8*)(Ab + ml * 256 + ((c16 ^ (ml & 15)) * 16));
            }
#pragma unroll
            for (int ks = 0; ks < 4; ++ks)
#pragma unroll
                for (int ni = 0; ni < 2; ++ni)
                    acc[ni] = __builtin_amdgcn_mfma_f32_32x32x16_bf16(afr[ks], bfr[s][ni][ks], acc[ni], 0, 0, 0);
        }
        __syncthreads();

        __bf16* Cs = (__bf16*)smem;
#pragma unroll
        for (int ni = 0; ni < 2; ++ni) {
            int col = w * 64 + ni * 32 + ml;
            float bv = bias1[col];
#pragma unroll
            for (int r = 0; r < 16; ++r) {
                int row = (r & 3) + 8 * (r >> 2) + 4 * kh;
                Cs[row * 264 + col] = (__bf16)elu_f(acc[ni][r] + bv);
            }
        }
        __syncthreads();

        bf16x8 a2[4];
#pragma unroll
        for (int ks = 0; ks < 4; ++ks)
            a2[ks] = *(const bf16x8*)&Cs[ml * 264 + w * 64 + ks * 16 + kh * 8];
        f32x16 acc2;
        { f32x16 z = {}; acc2 = z; }
#pragma unroll
        for (int ks = 0; ks < 4; ++ks)
            acc2 = __builtin_amdgcn_mfma_f32_32x32x16_bf16(a2[ks], b2f[ks], acc2, 0, 0, 0);
        __syncthreads();

        float* P = (float*)(smem + w * 4096);
#pragma unroll
        for (int r = 0; r < 16; ++r)
            P[((r & 3) + 8 * (r >> 2) + 4 * kh) * 32 + ml] = acc2[r];
        __syncthreads();

        float4 s4 = make_float4(0.f, 0.f, 0.f, 0.f);
#pragma unroll
        for (int pw = 0; pw < 4; ++pw) {
            float4 v = *(float4*)(smem + pw * 4096 + tid * 16);
            s4.x += v.x; s4.y += v.y; s4.z += v.z; s4.w += v.w;
        }
        __syncthreads();
        *(float4*)(smem + tid * 16) = s4;
        __syncthreads();

        if (tid < 32) {
            const float* L = (float*)smem + tid * 32;
            float logits[12], mx = -1e30f;
#pragma unroll
            for (int o = 0; o < 12; ++o) {
                logits[o] = L[o] + bias2[o];
                mx = fmaxf(mx, logits[o]);
            }
            float s = 0.f;
#pragma unroll
            for (int o = 0; o < 12; ++o) s += expf(logits[o] - mx);
            float lse = mx + logf(s);
            int n = mb + tid;
            float4 o0 = make_float4(logits[0] - lse, logits[1] - lse, logits[2] - lse, logits[3] - lse);
            float4 o1 = make_float4(logits[4] - lse, logits[5] - lse, logits[6] - lse, logits[7] - lse);
            float4 o2 = make_float4(logits[8] - lse, logits[9] - lse, logits[10] - lse, logits[11] - lse);
            *(float4*)&out[(size_t)n * 12 + 0] = o0;
            *(float4*)&out[(size_t)n * 12 + 4] = o1;
            *(float4*)&out[(size_t)n * 12 + 8] = o2;
        }
    }
}

extern "C" void kernel_launch(void* const* d_in, const int* in_sizes, int n_in,
                              void* d_out, int out_size, void* d_ws, size_t ws_size,
                              hipStream_t stream)
{
    const int N = 100000;
    const float* x     = (const float*)d_in[0];
    const int*   idx   = (const int*)  d_in[1];
    const float* fc0_w = (const float*)d_in[2];
    const float* fc0_b = (const float*)d_in[3];
    const float* w1    = (const float*)d_in[4];
    const float* b1    = (const float*)d_in[5];
    const float* w2    = (const float*)d_in[6];
    const float* b2    = (const float*)d_in[7];
    const float* w3    = (const float*)d_in[8];
    const float* b3    = (const float*)d_in[9];
    const float* fc1_w = (const float*)d_in[10];
    const float* fc1_b = (const float*)d_in[11];
    const float* fc2_w = (const float*)d_in[12];
    const float* fc2_b = (const float*)d_in[13];
    float* out = (float*)d_out;

    // ---- workspace layout
    char* ws = (char*)d_ws;
    const int n_w1 = 32 * 256, n_w2 = 64 * 512, n_w3 = 128 * 1024, n_fc1 = 256 * 128;
    const int n_fc2p = 32 * 256;
    const int n_wb = n_w1 + n_w2 + n_w3 + n_fc1 + n_fc2p;   // 212992
    __bf16* w1b = (__bf16*)ws;
    __bf16* w2b = w1b + n_w1;
    __bf16* w3b = w2b + n_w2;
    __bf16* f1b = w3b + n_w3;
    __bf16* f2b = f1b + n_fc1;
    size_t off = ((size_t)n_wb * 2 + 4095) & ~(size_t)4095;
    int* idxT = (int*)(ws + off);              off += (size_t)N * 16 * 4;
    __bf16* h0 = (__bf16*)(ws + off);          off += (size_t)N * 16 * 2;
    __bf16* h1 = (__bf16*)(ws + off);          off += (size_t)N * 32 * 2;
    unsigned char* h2f8 = (unsigned char*)(ws + off);  off += (size_t)N * 64;
    __bf16* h3 = (__bf16*)(ws + off);          off += (size_t)N * 128 * 2;

    // FUSED prep: weight swizzle (832 blocks) + idx transpose (6250) + fc0 (391).
    prep_kernel<<<7473, 256, 0, stream>>>(w1, w2, w3, fc1_w, fc2_w,
                                          w1b, w2b, w3b, f1b, f2b,
                                          idx, idxT, x, fc0_w, fc0_b, h0, N);

    // spiral1: 16ch x16 -> 32 bf16. TILE 128 (RW=4, CW=1), NSTEP=4, depth-2 hardened.
    mfma_layer<16, 16, 32, 32, 128, 4, 1, true, false, 3, 100000>
        <<<dim3((N + 127) / 128, 1), 256, 0, stream>>>(h0, idxT, w1b, b1, (void*)h1);
    // spiral2: 32ch x16 -> 64, OUTPUT fp8 h2. TILE 128 (RW=4, CW=1), NSTEP=8, depth-2 hardened.
    mfma_layer<32, 16, 64, 64, 128, 4, 1, true, true, 3, 100000>
        <<<dim3((N + 127) / 128, 1), 256, 0, stream>>>(h1, idxT, w2b, b2, (void*)h2f8);
    // spiral3 MIXED: fp8 h2 gather + bf16 w3 MFMA, HW dequant, TILE64 depth-2 (R20/R22 green).
    mfma3_mixed<<<(N + 63) / 64, 256, 0, stream>>>(h2f8, idxT, w3b, b3, h3);
    // FUSED fc1 + fc2(MFMA) + log_softmax, 64 rows/block.
    fc12_kernel<<<(N + 63) / 64, 256, 0, stream>>>(h3, f1b, fc1_b, f2b, fc2_b, out, N);
}

// Round 9
// 214.834 us; speedup vs baseline: 1.0277x; 1.0277x over previous
//
#include <hip/hip_runtime.h>
#include <hip/hip_fp8.h>
#include <math.h>
#include <utility>

// N = 100000 nodes, SEQ = 16, layers: 3 ->16 ->32 ->64 ->128 ->256 ->12(log_softmax)
// R26 (fuse fc12 into mfma3 tail):
//   mfma3's 64-row output tile == fc12's 64-row input block. The K-loop is
//   byte-identical to the twice-green R20/R22 kernel; ONLY the epilogue changes:
//   acc -> LDS in fc1's A-fragment layout (XOR-16 chunk swizzle, two 32-row
//   halves), then the R25-proven fc12 body runs in-block. h3 never materialized:
//   -25.6MB write, -25.6MB read, -1 dispatch. Numerics bit-identical.
//   Safety: tail weight loads cannot migrate INTO the loop (no mechanism moves
//   post-loop code into a loop); hardened/exact vmcnt waits tolerate extra OLDER
//   outstanding vmem by in-order retirement; spills avoided (tail ~160 VGPR
//   under launch_bounds(256,2) cap of 256). LDS 49664 (A-ring [0,24576) during
//   loop, repurposed after syncthreads).
// spiral1/2: R22-green hardened depth-2 mfma_layer (unchanged).
// prep fusion (R25), HW OCP-fp8 cvt + LDS chunk swizzle (R18) kept.

typedef __bf16 bf16x8 __attribute__((ext_vector_type(8)));
typedef float f32x16 __attribute__((ext_vector_type(16)));
typedef float f32x2 __attribute__((ext_vector_type(2)));

template <int V> using ic = std::integral_constant<int, V>;

template <typename F, int... Is>
__device__ __forceinline__ void static_for_impl(F&& f, std::integer_sequence<int, Is...>) {
    (f(ic<Is>{}), ...);
}
template <int N_, typename F>
__device__ __forceinline__ void static_for(F&& f) {
    static_for_impl(static_cast<F&&>(f), std::make_integer_sequence<int, N_>{});
}

template <int N_>
__device__ __forceinline__ void wait_vmcnt() {
    static_assert(N_ <= 63, "vmcnt range");
    __builtin_amdgcn_s_waitcnt((N_ & 0xF) | (0x7 << 4) | (0xF << 8) | ((N_ >> 4) << 14));
}

__device__ __forceinline__ void memfence_sched() { __builtin_amdgcn_sched_barrier(0x000F); }

__device__ __forceinline__ float elu_f(float v) { return v > 0.f ? v : expm1f(v); }

// HW encode: f32 -> OCP e4m3 (RNE, satfinite) via v_cvt_pk_fp8_f32, take byte 0.
__device__ __forceinline__ unsigned char to_fp8(float v) {
    int p = __builtin_amdgcn_cvt_pk_fp8_f32(v, v, 0, false);
    return (unsigned char)p;
}

__device__ __forceinline__ unsigned int pk_bf16(float a, float b) {
    unsigned int r;
    asm("v_cvt_pk_bf16_f32 %0, %1, %2" : "=v"(r) : "v"(a), "v"(b));
    return r;
}

// 8 packed fp8 e4m3 -> bf16x8, fully hardware: 4x v_cvt_pk_f32_fp8 + 4x v_cvt_pk_bf16_f32.
// Exact: every e4m3 value (incl. denormals) is representable in bf16.
__device__ __forceinline__ bf16x8 dq8(long v) {
    unsigned int lo = (unsigned int)(unsigned long)v;
    unsigned int hi = (unsigned int)((unsigned long)v >> 32);
    f32x2 f0 = __builtin_amdgcn_cvt_pk_f32_fp8((int)lo, false);
    f32x2 f1 = __builtin_amdgcn_cvt_pk_f32_fp8((int)lo, true);
    f32x2 f2 = __builtin_amdgcn_cvt_pk_f32_fp8((int)hi, false);
    f32x2 f3 = __builtin_amdgcn_cvt_pk_f32_fp8((int)hi, true);
    union { unsigned int u[4]; bf16x8 b; } r;
    r.u[0] = pk_bf16(f0[0], f0[1]);
    r.u[1] = pk_bf16(f1[0], f1[1]);
    r.u[2] = pk_bf16(f2[0], f2[1]);
    r.u[3] = pk_bf16(f3[0], f3[1]);
    return r.b;
}

// ------------------------------------------------ weight prep (all bf16 frag-major)
// dst chunk ((k/64)*8 + (k%64)/8)*C + col, elem k%8  <- src[col*K+k]
template <int K, int C>
__device__ __forceinline__ void swz_one(const float* __restrict__ src, __bf16* __restrict__ dst, int j)
{
    int col = j / K;
    int k = j & (K - 1);
    int chunk = ((k >> 6) * 8 + ((k & 63) >> 3)) * C + col;
    dst[chunk * 8 + (k & 7)] = (__bf16)src[j];
}

// ------------------------------------------------ FUSED prep: cvt_swz + idxT + fc0
// blocks [0,832): weight swizzle; [832,7082): idx transpose; [7082,7473): fc0.
__global__ __launch_bounds__(256) void prep_kernel(const float* __restrict__ w1,
                                                   const float* __restrict__ w2,
                                                   const float* __restrict__ w3,
                                                   const float* __restrict__ f1,
                                                   const float* __restrict__ f2,
                                                   __bf16* __restrict__ d1,
                                                   __bf16* __restrict__ d2,
                                                   __bf16* __restrict__ d3,
                                                   __bf16* __restrict__ df1,
                                                   __bf16* __restrict__ df2p,
                                                   const int* __restrict__ idx,
                                                   int* __restrict__ idxT,
                                                   const float* __restrict__ x,
                                                   const float* __restrict__ fc0_w,
                                                   const float* __restrict__ fc0_b,
                                                   __bf16* __restrict__ h0,
                                                   int N)
{
    int b = blockIdx.x;
    if (b < 832) {
        int i = b * 256 + threadIdx.x;   // < 212992
        if (i < 8192)        swz_one<256, 32>(w1, d1, i);
        else if (i < 40960)  swz_one<512, 64>(w2, d2, i - 8192);
        else if (i < 172032) swz_one<1024, 128>(w3, d3, i - 40960);
        else if (i < 204800) swz_one<128, 256>(f1, df1, i - 172032);
        else {
            // fc2 padded to 32 cols, frag-major (K=256, C=32); inverse map over DEST index
            int d = i - 204800;
            int e = d & 7;
            int chunkIdx = d >> 3;
            int col = chunkIdx & 31;
            int q = chunkIdx >> 5;
            int k = (q >> 3) * 64 + (q & 7) * 8 + e;
            df2p[d] = (col < 12) ? (__bf16)f2[col * 256 + k] : (__bf16)0.f;
        }
    } else if (b < 7082) {
        int i = (b - 832) * 256 + threadIdx.x;
        if (i < N * 16) {
            int n = i >> 4, s = i & 15;
            idxT[s * N + n] = idx[i];
        }
    } else {
        int n = (b - 7082) * 256 + threadIdx.x;
        if (n < N) {
            float x0 = x[n * 3 + 0], x1 = x[n * 3 + 1], x2 = x[n * 3 + 2];
            __bf16 ob[16];
#pragma unroll
            for (int j = 0; j < 16; ++j)
                ob[j] = (__bf16)elu_f(fc0_w[j * 3 + 0] * x0 + fc0_w[j * 3 + 1] * x1
                                      + fc0_w[j * 3 + 2] * x2 + fc0_b[j]);
            int4* dst = (int4*)&h0[(size_t)n * 16];
            dst[0] = *(int4*)&ob[0];
            dst[1] = *(int4*)&ob[8];
        }
    }
}

// ------------------------------------------- depth-2 wait-at-top bf16 MFMA gather-GEMM (R22)
// Hardened wait: NW = D*(s+1<NSTEP) + I*(s+3<NSTEP) counts ONLY the youngest two
// vmem groups -> always <= true outstanding-after-DMA(s) -> DMA(s) complete by
// in-order vmcnt retirement. DMA(s+1) prefetch stays in flight across the wait.
// OUTF8: epilogue emits fp8 e4m3 instead of bf16 (used by spiral2 -> h2).
template <int CIN, int S, int COUT_B, int COUT_TOT, int TILE_M, int RW, int CW,
          bool GATHER, bool OUTF8, int MINW, int NN>
__global__ __launch_bounds__(256, MINW) void mfma_layer(const __bf16* __restrict__ hin,
                                                        const int* __restrict__ idxT,
                                                        const __bf16* __restrict__ Wsw,
                                                        const float* __restrict__ bias,
                                                        void* __restrict__ hout)
{
    constexpr int K = CIN * S;
    constexpr int NSTEP = K / 64;
    static_assert(K % 64 == 0, "K%64");
    constexpr int WM = TILE_M / RW;
    constexpr int WN = COUT_B / CW;
    constexpr int MT = WM / 32;
    constexpr int NT = WN / 32;
    constexpr int IPS = GATHER ? (64 / CIN) : 1;
    constexpr int D = WM / 8;
    constexpr int Bn = NT * 4;
    constexpr int I = GATHER ? D : 0;
    constexpr int NBUFS = 3;
    static_assert(RW * CW == 4, "4 waves");
    static_assert(WM == 32 || WM == 64, "1-2 row subtiles per wave");

    constexpr int AB = 4 * NBUFS * WM * 128;
    constexpr int CB = OUTF8 ? TILE_M * (COUT_B + 16) : TILE_M * (COUT_B + 8) * 2;
    constexpr int SH = AB > CB ? AB : CB;
    __shared__ __align__(16) char smem[SH];

    const int tid = threadIdx.x;
    const int lane = tid & 63;
    const int w = tid >> 6;
    const int wr = w / CW;
    const int wc = w % CW;
    const int ml = lane & 31;
    const int kh = lane >> 5;
    const int m0 = blockIdx.x * TILE_M;
    const int col0 = blockIdx.y * COUT_B;
    const int rbase = m0 + wr * WM;

    char* const Aw = smem + w * (NBUFS * WM * 128);

    int ioff[GATHER ? D : 1];
    int koff[GATHER ? D : 1];
    int gmr[GATHER ? 1 : D];
    int coff[GATHER ? 1 : D];
#pragma unroll
    for (int i = 0; i < D; ++i) {
        int r = i * 8 + (lane >> 3);
        int c = (lane & 7) ^ (r & 7);
        int gm = rbase + r; if (gm >= NN) gm = NN - 1;
        if constexpr (GATHER) {
            ioff[i] = ((c * 8) / CIN) * NN + gm;
            koff[i] = (c * 8) & (CIN - 1);
        } else {
            gmr[i] = gm;
            coff[i] = c * 8;
        }
    }

    bf16x8 bfr[2][NT][4];
    int myIdx[GATHER ? 3 : 1][GATHER ? D : 1];

    const __bf16* wlane = Wsw + ((size_t)(col0 + wc * WN + ml) + (size_t)kh * COUT_TOT) * 8;

    auto loadB = [&](auto sc) {
        constexpr int s = decltype(sc)::value;
        if constexpr (s < NSTEP) {
#pragma unroll
            for (int ni = 0; ni < NT; ++ni)
#pragma unroll
                for (int ks = 0; ks < 4; ++ks)
                    bfr[s & 1][ni][ks] = *(const bf16x8*)(wlane
                        + (size_t)(s * 8 + ks * 2) * COUT_TOT * 8 + ni * 32 * 8);
        }
    };
    auto loadIdxS = [&](auto sc) {
        constexpr int s = decltype(sc)::value;
        if constexpr (GATHER && s < NSTEP) {
#pragma unroll
            for (int i = 0; i < D; ++i)
                myIdx[s % 3][i] = idxT[(s * IPS) * NN + ioff[i]];
        }
    };
    auto issueDMA = [&](auto sc) {
        constexpr int s = decltype(sc)::value;
        if constexpr (s < NSTEP) {
            char* base = Aw + (s % NBUFS) * (WM * 128);
#pragma unroll
            for (int i = 0; i < D; ++i) {
                const __bf16* src;
                if constexpr (GATHER)
                    src = hin + (size_t)myIdx[s % 3][i] * CIN + koff[i];
                else
                    src = hin + (size_t)gmr[i] * K + s * 64 + coff[i];
                __builtin_amdgcn_global_load_lds(
                    (const __attribute__((address_space(1))) void*)src,
                    (__attribute__((address_space(3))) void*)(base + i * 1024),
                    16, 0, 0);
            }
        }
    };

    f32x16 acc[MT][NT];
#pragma unroll
    for (int mi = 0; mi < MT; ++mi)
#pragma unroll
        for (int ni = 0; ni < NT; ++ni) { f32x16 z = {}; acc[mi][ni] = z; }

    // depth-2 prologue: idx0..2, B0, DMA0, DMA1, idx3
    loadIdxS(ic<0>{});
    loadIdxS(ic<1>{});
    loadIdxS(ic<2>{});
    memfence_sched();
    loadB(ic<0>{});
    memfence_sched();
    issueDMA(ic<0>{});
    memfence_sched();
    issueDMA(ic<1>{});
    memfence_sched();
    loadIdxS(ic<3>{});
    memfence_sched();

    static_for<NSTEP>([&](auto sc) {
        constexpr int s = decltype(sc)::value;
        // HARDENED wait-at-top: count only DMA(s+1) + idx(s+3), the youngest groups.
        constexpr int NW = D * (s + 1 < NSTEP) + I * (s + 3 < NSTEP);
        wait_vmcnt<NW>();
        memfence_sched();

        // ds_read A fragments (pinned between fences)
        const char* base = Aw + (s % NBUFS) * (WM * 128);
        bf16x8 afr[MT][4];
#pragma unroll
        for (int mi = 0; mi < MT; ++mi)
#pragma unroll
            for (int ks = 0; ks < 4; ++ks) {
                int cb = ks * 2 + kh;
                afr[mi][ks] = *(const bf16x8*)(base + ((mi * 32 + ml) * 8 + (cb ^ (ml & 7))) * 16);
            }
        memfence_sched();

        // issue next-iteration vmem while this iteration computes
        loadB(ic<s + 1>{});
        memfence_sched();
        issueDMA(ic<s + 2>{});
        memfence_sched();
        loadIdxS(ic<s + 4>{});
        memfence_sched();

#pragma unroll
        for (int ks = 0; ks < 4; ++ks)
#pragma unroll
            for (int mi = 0; mi < MT; ++mi)
#pragma unroll
                for (int ni = 0; ni < NT; ++ni)
                    acc[mi][ni] = __builtin_amdgcn_mfma_f32_32x32x16_bf16(
                        afr[mi][ks], bfr[s & 1][ni][ks], acc[mi][ni], 0, 0, 0);
    });

    // ---- epilogue
    __syncthreads();
    if constexpr (OUTF8) {
        unsigned char* Cs8 = (unsigned char*)smem;
        constexpr int LDC8 = COUT_B + 16;
#pragma unroll
        for (int ni = 0; ni < NT; ++ni) {
            const int col = wc * WN + ni * 32 + ml;
            const float bv = bias[col0 + col];
#pragma unroll
            for (int mi = 0; mi < MT; ++mi) {
#pragma unroll
                for (int r = 0; r < 16; ++r) {
                    int row = wr * WM + mi * 32 + ((r & 3) + 8 * (r >> 2) + 4 * kh);
                    Cs8[row * LDC8 + col] = to_fp8(elu_f(acc[mi][ni][r] + bv));
                }
            }
        }
        __syncthreads();
        constexpr int C16 = COUT_B / 16;
#pragma unroll
        for (int j2 = tid; j2 < TILE_M * C16; j2 += 256) {
            int row = j2 / C16, c16 = j2 % C16;
            int gm = m0 + row;
            if (gm < NN)
                *(int4*)((unsigned char*)hout + (size_t)gm * COUT_TOT + col0 + c16 * 16)
                    = *(int4*)&Cs8[row * LDC8 + c16 * 16];
        }
    } else {
        __bf16* Cs = (__bf16*)smem;
        constexpr int LDC = COUT_B + 8;
#pragma unroll
        for (int ni = 0; ni < NT; ++ni) {
            const int col = wc * WN + ni * 32 + ml;
            const float bv = bias[col0 + col];
#pragma unroll
            for (int mi = 0; mi < MT; ++mi) {
#pragma unroll
                for (int r = 0; r < 16; ++r) {
                    int row = wr * WM + mi * 32 + ((r & 3) + 8 * (r >> 2) + 4 * kh);
                    Cs[row * LDC + col] = (__bf16)elu_f(acc[mi][ni][r] + bv);
                }
            }
        }
        __syncthreads();
        constexpr int C8 = COUT_B / 8;
#pragma unroll
        for (int j2 = tid; j2 < TILE_M * C8; j2 += 256) {
            int row = j2 / C8, c8 = j2 % C8;
            int gm = m0 + row;
            if (gm < NN)
                *(int4*)&((__bf16*)hout)[(size_t)gm * COUT_TOT + col0 + c8 * 8] = *(int4*)&Cs[row * LDC + c8 * 8];
        }
    }
}

// ------------------------------------------- spiral3 MIXED + FUSED fc1/fc2/log_softmax
// K-loop: EXACT R20/R22-green kernel (TILE 64, RW=2/CW=2, wave 32x64, K=1024,
// NSTEP=16, depth-2 NBUFS=3, wait-at-top, R20 NW formula) -- DO NOT TOUCH.
// Fused tail (R26): acc -> LDS in fc1 A-layout (byte (r,k) = r*256 +
// ((k>>3)^(r&15))*16 + (k&7)*2; half = wr at base wr*8192), then the R25-proven
// fc12 body per 32-row half. h3 never hits global memory.
// LDS map: loop A-ring [0,24576). Tail: h3A [0,8192) h3B [8192,16384)
// Cs2 [16384,33280) P/L [33280,49664).
__global__ __launch_bounds__(256, 2) void mfma3_fused(const unsigned char* __restrict__ h2f8, // [N,64] e4m3
                                                      const int* __restrict__ idxT,
                                                      const __bf16* __restrict__ Wsw,   // w3 frag-major (K=1024,C=128)
                                                      const float* __restrict__ bias3,
                                                      const __bf16* __restrict__ Wf1,   // fc1 frag-major (K=128,C=256)
                                                      const float* __restrict__ bias1,
                                                      const __bf16* __restrict__ W2p,   // fc2 frag-major padded (K=256,C=32)
                                                      const float* __restrict__ bias2,
                                                      float* __restrict__ out)
{
    constexpr int NN = 100000;
    constexpr int NSTEP = 16;
    constexpr int D = 2;        // DMA insts per step per wave (32 rows x 64 B)
    constexpr int Bn = 8;       // B vmem loads per step
    constexpr int I = 2;        // idx loads per step
    constexpr int NBUFS = 3;
    __shared__ __align__(16) char smem[49664];

    const int tid = threadIdx.x;
    const int lane = tid & 63;
    const int w = tid >> 6;
    const int wr = w >> 1;
    const int wc = w & 1;
    const int ml = lane & 31;
    const int kh = lane >> 5;
    const int m0 = blockIdx.x * 64;
    const int rbase = m0 + wr * 32;

    char* const Aw = smem + w * (NBUFS * 2048);

    // DMA geometry: inst i, lane t -> row r=i*16+(t>>2), phys chunk t&3 holds src chunk
    // (t&3) ^ (r&3) ^ ((r>>2)&3)
    int ioff[D], koff[D];
#pragma unroll
    for (int i = 0; i < D; ++i) {
        int r = i * 16 + (lane >> 2);
        int c = (lane & 3) ^ (r & 3) ^ ((r >> 2) & 3);
        int gm = rbase + r; if (gm >= NN) gm = NN - 1;
        ioff[i] = gm;
        koff[i] = c * 16;
    }

    bf16x8 bfr[2][2][4];
    int myIdx[3][D];

    const __bf16* wlane = Wsw + ((size_t)(wc * 64 + ml) + (size_t)kh * 128) * 8;

    auto loadB = [&](auto sc) {
        constexpr int s = decltype(sc)::value;
        if constexpr (s < NSTEP) {
#pragma unroll
            for (int ni = 0; ni < 2; ++ni)
#pragma unroll
                for (int ks = 0; ks < 4; ++ks)
                    bfr[s & 1][ni][ks] = *(const bf16x8*)(wlane
                        + (size_t)(s * 8 + ks * 2) * 128 * 8 + ni * 32 * 8);
        }
    };
    auto loadIdxS = [&](auto sc) {
        constexpr int s = decltype(sc)::value;
        if constexpr (s < NSTEP) {
#pragma unroll
            for (int i = 0; i < D; ++i)
                myIdx[s % 3][i] = idxT[(size_t)s * NN + ioff[i]];
        }
    };
    auto issueDMA = [&](auto sc) {
        constexpr int s = decltype(sc)::value;
        if constexpr (s < NSTEP) {
            char* base = Aw + (s % NBUFS) * 2048;
#pragma unroll
            for (int i = 0; i < D; ++i) {
                const unsigned char* src = h2f8 + (size_t)myIdx[s % 3][i] * 64 + koff[i];
                __builtin_amdgcn_global_load_lds(
                    (const __attribute__((address_space(1))) void*)src,
                    (__attribute__((address_space(3))) void*)(base + i * 1024),
                    16, 0, 0);
            }
        }
    };

    f32x16 acc[2];
    { f32x16 z = {}; acc[0] = z; acc[1] = z; }

    // depth-2 prologue: idx0..2, B0, DMA0, DMA1, idx3
    loadIdxS(ic<0>{});
    loadIdxS(ic<1>{});
    loadIdxS(ic<2>{});
    memfence_sched();
    loadB(ic<0>{});
    memfence_sched();
    issueDMA(ic<0>{});
    memfence_sched();
    issueDMA(ic<1>{});
    memfence_sched();
    loadIdxS(ic<3>{});
    memfence_sched();

    static_for<NSTEP>([&](auto sc) {
        constexpr int s = decltype(sc)::value;
        // wait for DMA(s) at iteration TOP. Ops issued after DMA(s):
        //  s==0 (prologue): DMA(1)=D, idx(3)=I.
        //  s>=1: idx(s+2) [iter s-2] + B(s) [iter s-1, always] + DMA(s+1) + idx(s+3).
        constexpr int NW = (s == 0)
            ? (D * (1 < NSTEP) + I * (3 < NSTEP))
            : (I * (s + 2 < NSTEP) + Bn + D * (s + 1 < NSTEP) + I * (s + 3 < NSTEP));
        wait_vmcnt<NW>();
        memfence_sched();

        // ds_read raw fp8 rows (pinned between fences: cannot move above the wait)
        const char* base = Aw + (s % NBUFS) * 2048;
        long a8[4];
#pragma unroll
        for (int ks = 0; ks < 4; ++ks)
            a8[ks] = *(const long*)(base + ml * 64
                + (((ks ^ (ml & 3)) ^ ((ml >> 2) & 3)) << 4) + kh * 8);
        memfence_sched();

        // issue next-iteration vmem while this iteration computes
        loadB(ic<s + 1>{});
        memfence_sched();
        issueDMA(ic<s + 2>{});
        memfence_sched();
        loadIdxS(ic<s + 4>{});
        memfence_sched();

        bf16x8 afr[4];
#pragma unroll
        for (int ks = 0; ks < 4; ++ks)
            afr[ks] = dq8(a8[ks]);   // HW fp8 e4m3 -> bf16 (exact)
#pragma unroll
        for (int ks = 0; ks < 4; ++ks)
#pragma unroll
            for (int ni = 0; ni < 2; ++ni)
                acc[ni] = __builtin_amdgcn_mfma_f32_32x32x16_bf16(
                    afr[ks], bfr[s & 1][ni][ks], acc[ni], 0, 0, 0);
    });

    // ---- fused tail: h3-tile -> LDS in fc1 A-layout, then fc1+fc2+log_softmax
    __syncthreads();
    {
        // wave (wr,wc) computed h3 rows wr*32+crow(r), cols wc*64+ni*32+ml.
        // fc1-A layout byte (r16 in [0,32), k in [0,128)):
        //   r16*256 + ((k>>3) ^ (r16&15))*16 + (k&7)*2, half base = wr*8192.
        char* Ah = smem + wr * 8192;
#pragma unroll
        for (int ni = 0; ni < 2; ++ni) {
            const int col = wc * 64 + ni * 32 + ml;
            const float bv = bias3[col];
#pragma unroll
            for (int r = 0; r < 16; ++r) {
                int r16 = (r & 3) + 8 * (r >> 2) + 4 * kh;
                *(__bf16*)(Ah + r16 * 256 + (((col >> 3) ^ (r16 & 15)) << 4) + (col & 7) * 2)
                    = (__bf16)elu_f(acc[ni][r] + bv);
            }
        }
    }
    __syncthreads();

    // fc2 B fragments (loaded once; cannot migrate into the K-loop -- post-loop code)
    bf16x8 b2f[4];
#pragma unroll
    for (int ks = 0; ks < 4; ++ks)
        b2f[ks] = *(const bf16x8*)&W2p[((w * 8 + ks * 2 + kh) * 32 + ml) * 8];

    const __bf16* wlane1 = Wf1 + ((size_t)(w * 64 + ml) + (size_t)kh * 256) * 8;
    __bf16* Cs2 = (__bf16*)(smem + 16384);
    char* Pbase = smem + 33280;

#pragma unroll
    for (int half = 0; half < 2; ++half) {
        const char* Ab = smem + half * 8192;

        f32x16 acc1[2];
        { f32x16 z = {}; acc1[0] = z; acc1[1] = z; }
#pragma unroll
        for (int s = 0; s < 2; ++s) {
            bf16x8 afr1[4];
#pragma unroll
            for (int ks = 0; ks < 4; ++ks) {
                int c16 = s * 8 + ks * 2 + kh;
                afr1[ks] = *(const bf16x8*)(Ab + ml * 256 + ((c16 ^ (ml & 15)) * 16));
            }
            bf16x8 bfr1[2][4];
#pragma unroll
            for (int ni = 0; ni < 2; ++ni)
#pragma unroll
                for (int ks = 0; ks < 4; ++ks)
                    bfr1[ni][ks] = *(const bf16x8*)(wlane1
                        + (size_t)(s * 8 + ks * 2) * 256 * 8 + ni * 32 * 8);
#pragma unroll
            for (int ks = 0; ks < 4; ++ks)
#pragma unroll
                for (int ni = 0; ni < 2; ++ni)
                    acc1[ni] = __builtin_amdgcn_mfma_f32_32x32x16_bf16(
                        afr1[ks], bfr1[ni][ks], acc1[ni], 0, 0, 0);
        }
        __syncthreads();   // protect Cs2 from previous half's readers

#pragma unroll
        for (int ni = 0; ni < 2; ++ni) {
            int col = w * 64 + ni * 32 + ml;
            float bv = bias1[col];
#pragma unroll
            for (int r = 0; r < 16; ++r) {
                int row = (r & 3) + 8 * (r >> 2) + 4 * kh;
                Cs2[row * 264 + col] = (__bf16)elu_f(acc1[ni][r] + bv);
            }
        }
        __syncthreads();

        bf16x8 a2[4];
#pragma unroll
        for (int ks = 0; ks < 4; ++ks)
            a2[ks] = *(const bf16x8*)&Cs2[ml * 264 + w * 64 + ks * 16 + kh * 8];
        f32x16 acc2;
        { f32x16 z = {}; acc2 = z; }
#pragma unroll
        for (int ks = 0; ks < 4; ++ks)
            acc2 = __builtin_amdgcn_mfma_f32_32x32x16_bf16(a2[ks], b2f[ks], acc2, 0, 0, 0);
        __syncthreads();

        float* P = (float*)(Pbase + w * 4096);
#pragma unroll
        for (int r = 0; r < 16; ++r)
            P[((r & 3) + 8 * (r >> 2) + 4 * kh) * 32 + ml] = acc2[r];
        __syncthreads();

        float4 s4 = make_float4(0.f, 0.f, 0.f, 0.f);
#pragma unroll
        for (int pw = 0; pw < 4; ++pw) {
            float4 v = *(float4*)(Pbase + pw * 4096 + tid * 16);
            s4.x += v.x; s4.y += v.y; s4.z += v.z; s4.w += v.w;
        }
        __syncthreads();
        *(float4*)(Pbase + tid * 16) = s4;
        __syncthreads();

        if (tid < 32) {
            int n = m0 + half * 32 + tid;
            if (n < NN) {
                const float* L = (float*)Pbase + tid * 32;
                float logits[12], mx = -1e30f;
#pragma unroll
                for (int o = 0; o < 12; ++o) {
                    logits[o] = L[o] + bias2[o];
                    mx = fmaxf(mx, logits[o]);
                }
                float s = 0.f;
#pragma unroll
                for (int o = 0; o < 12; ++o) s += expf(logits[o] - mx);
                float lse = mx + logf(s);
                float4 o0 = make_float4(logits[0] - lse, logits[1] - lse, logits[2] - lse, logits[3] - lse);
                float4 o1 = make_float4(logits[4] - lse, logits[5] - lse, logits[6] - lse, logits[7] - lse);
                float4 o2 = make_float4(logits[8] - lse, logits[9] - lse, logits[10] - lse, logits[11] - lse);
                *(float4*)&out[(size_t)n * 12 + 0] = o0;
                *(float4*)&out[(size_t)n * 12 + 4] = o1;
                *(float4*)&out[(size_t)n * 12 + 8] = o2;
            }
        }
    }
}

extern "C" void kernel_launch(void* const* d_in, const int* in_sizes, int n_in,
                              void* d_out, int out_size, void* d_ws, size_t ws_size,
                              hipStream_t stream)
{
    const int N = 100000;
    const float* x     = (const float*)d_in[0];
    const int*   idx   = (const int*)  d_in[1];
    const float* fc0_w = (const float*)d_in[2];
    const float* fc0_b = (const float*)d_in[3];
    const float* w1    = (const float*)d_in[4];
    const float* b1    = (const float*)d_in[5];
    const float* w2    = (const float*)d_in[6];
    const float* b2    = (const float*)d_in[7];
    const float* w3    = (const float*)d_in[8];
    const float* b3    = (const float*)d_in[9];
    const float* fc1_w = (const float*)d_in[10];
    const float* fc1_b = (const float*)d_in[11];
    const float* fc2_w = (const float*)d_in[12];
    const float* fc2_b = (const float*)d_in[13];
    float* out = (float*)d_out;

    // ---- workspace layout
    char* ws = (char*)d_ws;
    const int n_w1 = 32 * 256, n_w2 = 64 * 512, n_w3 = 128 * 1024, n_fc1 = 256 * 128;
    const int n_fc2p = 32 * 256;
    const int n_wb = n_w1 + n_w2 + n_w3 + n_fc1 + n_fc2p;   // 212992
    __bf16* w1b = (__bf16*)ws;
    __bf16* w2b = w1b + n_w1;
    __bf16* w3b = w2b + n_w2;
    __bf16* f1b = w3b + n_w3;
    __bf16* f2b = f1b + n_fc1;
    size_t off = ((size_t)n_wb * 2 + 4095) & ~(size_t)4095;
    int* idxT = (int*)(ws + off);              off += (size_t)N * 16 * 4;
    __bf16* h0 = (__bf16*)(ws + off);          off += (size_t)N * 16 * 2;
    __bf16* h1 = (__bf16*)(ws + off);          off += (size_t)N * 32 * 2;
    unsigned char* h2f8 = (unsigned char*)(ws + off);  off += (size_t)N * 64;

    // FUSED prep: weight swizzle (832 blocks) + idx transpose (6250) + fc0 (391).
    prep_kernel<<<7473, 256, 0, stream>>>(w1, w2, w3, fc1_w, fc2_w,
                                          w1b, w2b, w3b, f1b, f2b,
                                          idx, idxT, x, fc0_w, fc0_b, h0, N);

    // spiral1: 16ch x16 -> 32 bf16. TILE 128 (RW=4, CW=1), NSTEP=4, depth-2 hardened.
    mfma_layer<16, 16, 32, 32, 128, 4, 1, true, false, 3, 100000>
        <<<dim3((N + 127) / 128, 1), 256, 0, stream>>>(h0, idxT, w1b, b1, (void*)h1);
    // spiral2: 32ch x16 -> 64, OUTPUT fp8 h2. TILE 128 (RW=4, CW=1), NSTEP=8, depth-2 hardened.
    mfma_layer<32, 16, 64, 64, 128, 4, 1, true, true, 3, 100000>
        <<<dim3((N + 127) / 128, 1), 256, 0, stream>>>(h1, idxT, w2b, b2, (void*)h2f8);
    // spiral3 MIXED + fused fc1/fc2/log_softmax (h3 never materialized).
    mfma3_fused<<<(N + 63) / 64, 256, 0, stream>>>(h2f8, idxT, w3b, b3,
                                                   f1b, fc1_b, f2b, fc2_b, out);
}

// Round 10
// 214.639 us; speedup vs baseline: 1.0287x; 1.0009x over previous
//
#include <hip/hip_runtime.h>
#include <hip/hip_fp8.h>
#include <math.h>
#include <utility>

// N = 100000 nodes, SEQ = 16, layers: 3 ->16 ->32 ->64 ->128 ->256 ->12(log_softmax)
// R27 (LDS diet + coalesced idxT):
//   - mfma3_fused tail: P-reduction buffer ALIASED onto Cs2 (never simultaneously
//     live -- existing barriers already separate last-read from first-write both
//     directions). LDS 49664 -> 33280 => 4 blocks/CU (was 3). More resident waves
//     = more gather memory-level-parallelism for the latency-bound K-loop.
//   - prep idxT: LDS-staged transpose (pad 260) -> both read and write coalesced
//     (old version wrote scattered 16B segments over 6.4MB).
//   K-loop & all vmcnt structures byte-identical to R26-green.
// R26 kept: fc12 fused into mfma3 tail (h3 never materialized).
// spiral1/2: R22-green hardened depth-2 mfma_layer. HW OCP-fp8 cvt (R18).

typedef __bf16 bf16x8 __attribute__((ext_vector_type(8)));
typedef float f32x16 __attribute__((ext_vector_type(16)));
typedef float f32x2 __attribute__((ext_vector_type(2)));

template <int V> using ic = std::integral_constant<int, V>;

template <typename F, int... Is>
__device__ __forceinline__ void static_for_impl(F&& f, std::integer_sequence<int, Is...>) {
    (f(ic<Is>{}), ...);
}
template <int N_, typename F>
__device__ __forceinline__ void static_for(F&& f) {
    static_for_impl(static_cast<F&&>(f), std::make_integer_sequence<int, N_>{});
}

template <int N_>
__device__ __forceinline__ void wait_vmcnt() {
    static_assert(N_ <= 63, "vmcnt range");
    __builtin_amdgcn_s_waitcnt((N_ & 0xF) | (0x7 << 4) | (0xF << 8) | ((N_ >> 4) << 14));
}

__device__ __forceinline__ void memfence_sched() { __builtin_amdgcn_sched_barrier(0x000F); }

__device__ __forceinline__ float elu_f(float v) { return v > 0.f ? v : expm1f(v); }

// HW encode: f32 -> OCP e4m3 (RNE, satfinite) via v_cvt_pk_fp8_f32, take byte 0.
__device__ __forceinline__ unsigned char to_fp8(float v) {
    int p = __builtin_amdgcn_cvt_pk_fp8_f32(v, v, 0, false);
    return (unsigned char)p;
}

__device__ __forceinline__ unsigned int pk_bf16(float a, float b) {
    unsigned int r;
    asm("v_cvt_pk_bf16_f32 %0, %1, %2" : "=v"(r) : "v"(a), "v"(b));
    return r;
}

// 8 packed fp8 e4m3 -> bf16x8, fully hardware: 4x v_cvt_pk_f32_fp8 + 4x v_cvt_pk_bf16_f32.
// Exact: every e4m3 value (incl. denormals) is representable in bf16.
__device__ __forceinline__ bf16x8 dq8(long v) {
    unsigned int lo = (unsigned int)(unsigned long)v;
    unsigned int hi = (unsigned int)((unsigned long)v >> 32);
    f32x2 f0 = __builtin_amdgcn_cvt_pk_f32_fp8((int)lo, false);
    f32x2 f1 = __builtin_amdgcn_cvt_pk_f32_fp8((int)lo, true);
    f32x2 f2 = __builtin_amdgcn_cvt_pk_f32_fp8((int)hi, false);
    f32x2 f3 = __builtin_amdgcn_cvt_pk_f32_fp8((int)hi, true);
    union { unsigned int u[4]; bf16x8 b; } r;
    r.u[0] = pk_bf16(f0[0], f0[1]);
    r.u[1] = pk_bf16(f1[0], f1[1]);
    r.u[2] = pk_bf16(f2[0], f2[1]);
    r.u[3] = pk_bf16(f3[0], f3[1]);
    return r.b;
}

// ------------------------------------------------ weight prep (all bf16 frag-major)
// dst chunk ((k/64)*8 + (k%64)/8)*C + col, elem k%8  <- src[col*K+k]
template <int K, int C>
__device__ __forceinline__ void swz_one(const float* __restrict__ src, __bf16* __restrict__ dst, int j)
{
    int col = j / K;
    int k = j & (K - 1);
    int chunk = ((k >> 6) * 8 + ((k & 63) >> 3)) * C + col;
    dst[chunk * 8 + (k & 7)] = (__bf16)src[j];
}

// ------------------------------------------------ FUSED prep: cvt_swz + idxT + fc0
// blocks [0,832): weight swizzle; [832,1223): idxT (LDS transpose, 4096/block);
// [1223,1614): fc0 (256 nodes/block).
__global__ __launch_bounds__(256) void prep_kernel(const float* __restrict__ w1,
                                                   const float* __restrict__ w2,
                                                   const float* __restrict__ w3,
                                                   const float* __restrict__ f1,
                                                   const float* __restrict__ f2,
                                                   __bf16* __restrict__ d1,
                                                   __bf16* __restrict__ d2,
                                                   __bf16* __restrict__ d3,
                                                   __bf16* __restrict__ df1,
                                                   __bf16* __restrict__ df2p,
                                                   const int* __restrict__ idx,
                                                   int* __restrict__ idxT,
                                                   const float* __restrict__ x,
                                                   const float* __restrict__ fc0_w,
                                                   const float* __restrict__ fc0_b,
                                                   __bf16* __restrict__ h0,
                                                   int N)
{
    __shared__ int tlds[16 * 260];
    int b = blockIdx.x;
    int t = threadIdx.x;
    if (b < 832) {
        int i = b * 256 + t;             // < 212992
        if (i < 8192)        swz_one<256, 32>(w1, d1, i);
        else if (i < 40960)  swz_one<512, 64>(w2, d2, i - 8192);
        else if (i < 172032) swz_one<1024, 128>(w3, d3, i - 40960);
        else if (i < 204800) swz_one<128, 256>(f1, df1, i - 172032);
        else {
            // fc2 padded to 32 cols, frag-major (K=256, C=32); inverse map over DEST index
            int d = i - 204800;
            int e = d & 7;
            int chunkIdx = d >> 3;
            int col = chunkIdx & 31;
            int q = chunkIdx >> 5;
            int k = (q >> 3) * 64 + (q & 7) * 8 + e;
            df2p[d] = (col < 12) ? (__bf16)f2[col * 256 + k] : (__bf16)0.f;
        }
    } else if (b < 1223) {
        // idxT via LDS: block handles 256 nodes x 16 slots, both sides coalesced.
        const int base = (b - 832) * 4096;      // entry index, multiple of 4096
        const int nbase = base >> 4;            // node base (multiple of 256)
#pragma unroll
        for (int k = 0; k < 16; ++k) {
            int local = k * 256 + t;
            int g = base + local;
            int v = (g < N * 16) ? idx[g] : 0;
            // s = local&15 (=t&15), col = local>>4 = k*16 + (t>>4)
            tlds[(t & 15) * 260 + k * 16 + (t >> 4)] = v;
        }
        __syncthreads();
        if (nbase + t < N) {
#pragma unroll
            for (int s2 = 0; s2 < 16; ++s2)
                idxT[(size_t)s2 * N + nbase + t] = tlds[s2 * 260 + t];
        }
    } else {
        int n = (b - 1223) * 256 + t;
        if (n < N) {
            float x0 = x[n * 3 + 0], x1 = x[n * 3 + 1], x2 = x[n * 3 + 2];
            __bf16 ob[16];
#pragma unroll
            for (int j = 0; j < 16; ++j)
                ob[j] = (__bf16)elu_f(fc0_w[j * 3 + 0] * x0 + fc0_w[j * 3 + 1] * x1
                                      + fc0_w[j * 3 + 2] * x2 + fc0_b[j]);
            int4* dst = (int4*)&h0[(size_t)n * 16];
            dst[0] = *(int4*)&ob[0];
            dst[1] = *(int4*)&ob[8];
        }
    }
}

// ------------------------------------------- depth-2 wait-at-top bf16 MFMA gather-GEMM (R22)
// Hardened wait: NW = D*(s+1<NSTEP) + I*(s+3<NSTEP) counts ONLY the youngest two
// vmem groups -> always <= true outstanding-after-DMA(s) -> DMA(s) complete by
// in-order vmcnt retirement. DMA(s+1) prefetch stays in flight across the wait.
// OUTF8: epilogue emits fp8 e4m3 instead of bf16 (used by spiral2 -> h2).
template <int CIN, int S, int COUT_B, int COUT_TOT, int TILE_M, int RW, int CW,
          bool GATHER, bool OUTF8, int MINW, int NN>
__global__ __launch_bounds__(256, MINW) void mfma_layer(const __bf16* __restrict__ hin,
                                                        const int* __restrict__ idxT,
                                                        const __bf16* __restrict__ Wsw,
                                                        const float* __restrict__ bias,
                                                        void* __restrict__ hout)
{
    constexpr int K = CIN * S;
    constexpr int NSTEP = K / 64;
    static_assert(K % 64 == 0, "K%64");
    constexpr int WM = TILE_M / RW;
    constexpr int WN = COUT_B / CW;
    constexpr int MT = WM / 32;
    constexpr int NT = WN / 32;
    constexpr int IPS = GATHER ? (64 / CIN) : 1;
    constexpr int D = WM / 8;
    constexpr int Bn = NT * 4;
    constexpr int I = GATHER ? D : 0;
    constexpr int NBUFS = 3;
    static_assert(RW * CW == 4, "4 waves");
    static_assert(WM == 32 || WM == 64, "1-2 row subtiles per wave");

    constexpr int AB = 4 * NBUFS * WM * 128;
    constexpr int CB = OUTF8 ? TILE_M * (COUT_B + 16) : TILE_M * (COUT_B + 8) * 2;
    constexpr int SH = AB > CB ? AB : CB;
    __shared__ __align__(16) char smem[SH];

    const int tid = threadIdx.x;
    const int lane = tid & 63;
    const int w = tid >> 6;
    const int wr = w / CW;
    const int wc = w % CW;
    const int ml = lane & 31;
    const int kh = lane >> 5;
    const int m0 = blockIdx.x * TILE_M;
    const int col0 = blockIdx.y * COUT_B;
    const int rbase = m0 + wr * WM;

    char* const Aw = smem + w * (NBUFS * WM * 128);

    int ioff[GATHER ? D : 1];
    int koff[GATHER ? D : 1];
    int gmr[GATHER ? 1 : D];
    int coff[GATHER ? 1 : D];
#pragma unroll
    for (int i = 0; i < D; ++i) {
        int r = i * 8 + (lane >> 3);
        int c = (lane & 7) ^ (r & 7);
        int gm = rbase + r; if (gm >= NN) gm = NN - 1;
        if constexpr (GATHER) {
            ioff[i] = ((c * 8) / CIN) * NN + gm;
            koff[i] = (c * 8) & (CIN - 1);
        } else {
            gmr[i] = gm;
            coff[i] = c * 8;
        }
    }

    bf16x8 bfr[2][NT][4];
    int myIdx[GATHER ? 3 : 1][GATHER ? D : 1];

    const __bf16* wlane = Wsw + ((size_t)(col0 + wc * WN + ml) + (size_t)kh * COUT_TOT) * 8;

    auto loadB = [&](auto sc) {
        constexpr int s = decltype(sc)::value;
        if constexpr (s < NSTEP) {
#pragma unroll
            for (int ni = 0; ni < NT; ++ni)
#pragma unroll
                for (int ks = 0; ks < 4; ++ks)
                    bfr[s & 1][ni][ks] = *(const bf16x8*)(wlane
                        + (size_t)(s * 8 + ks * 2) * COUT_TOT * 8 + ni * 32 * 8);
        }
    };
    auto loadIdxS = [&](auto sc) {
        constexpr int s = decltype(sc)::value;
        if constexpr (GATHER && s < NSTEP) {
#pragma unroll
            for (int i = 0; i < D; ++i)
                myIdx[s % 3][i] = idxT[(s * IPS) * NN + ioff[i]];
        }
    };
    auto issueDMA = [&](auto sc) {
        constexpr int s = decltype(sc)::value;
        if constexpr (s < NSTEP) {
            char* base = Aw + (s % NBUFS) * (WM * 128);
#pragma unroll
            for (int i = 0; i < D; ++i) {
                const __bf16* src;
                if constexpr (GATHER)
                    src = hin + (size_t)myIdx[s % 3][i] * CIN + koff[i];
                else
                    src = hin + (size_t)gmr[i] * K + s * 64 + coff[i];
                __builtin_amdgcn_global_load_lds(
                    (const __attribute__((address_space(1))) void*)src,
                    (__attribute__((address_space(3))) void*)(base + i * 1024),
                    16, 0, 0);
            }
        }
    };

    f32x16 acc[MT][NT];
#pragma unroll
    for (int mi = 0; mi < MT; ++mi)
#pragma unroll
        for (int ni = 0; ni < NT; ++ni) { f32x16 z = {}; acc[mi][ni] = z; }

    // depth-2 prologue: idx0..2, B0, DMA0, DMA1, idx3
    loadIdxS(ic<0>{});
    loadIdxS(ic<1>{});
    loadIdxS(ic<2>{});
    memfence_sched();
    loadB(ic<0>{});
    memfence_sched();
    issueDMA(ic<0>{});
    memfence_sched();
    issueDMA(ic<1>{});
    memfence_sched();
    loadIdxS(ic<3>{});
    memfence_sched();

    static_for<NSTEP>([&](auto sc) {
        constexpr int s = decltype(sc)::value;
        // HARDENED wait-at-top: count only DMA(s+1) + idx(s+3), the youngest groups.
        constexpr int NW = D * (s + 1 < NSTEP) + I * (s + 3 < NSTEP);
        wait_vmcnt<NW>();
        memfence_sched();

        // ds_read A fragments (pinned between fences)
        const char* base = Aw + (s % NBUFS) * (WM * 128);
        bf16x8 afr[MT][4];
#pragma unroll
        for (int mi = 0; mi < MT; ++mi)
#pragma unroll
            for (int ks = 0; ks < 4; ++ks) {
                int cb = ks * 2 + kh;
                afr[mi][ks] = *(const bf16x8*)(base + ((mi * 32 + ml) * 8 + (cb ^ (ml & 7))) * 16);
            }
        memfence_sched();

        // issue next-iteration vmem while this iteration computes
        loadB(ic<s + 1>{});
        memfence_sched();
        issueDMA(ic<s + 2>{});
        memfence_sched();
        loadIdxS(ic<s + 4>{});
        memfence_sched();

#pragma unroll
        for (int ks = 0; ks < 4; ++ks)
#pragma unroll
            for (int mi = 0; mi < MT; ++mi)
#pragma unroll
                for (int ni = 0; ni < NT; ++ni)
                    acc[mi][ni] = __builtin_amdgcn_mfma_f32_32x32x16_bf16(
                        afr[mi][ks], bfr[s & 1][ni][ks], acc[mi][ni], 0, 0, 0);
    });

    // ---- epilogue
    __syncthreads();
    if constexpr (OUTF8) {
        unsigned char* Cs8 = (unsigned char*)smem;
        constexpr int LDC8 = COUT_B + 16;
#pragma unroll
        for (int ni = 0; ni < NT; ++ni) {
            const int col = wc * WN + ni * 32 + ml;
            const float bv = bias[col0 + col];
#pragma unroll
            for (int mi = 0; mi < MT; ++mi) {
#pragma unroll
                for (int r = 0; r < 16; ++r) {
                    int row = wr * WM + mi * 32 + ((r & 3) + 8 * (r >> 2) + 4 * kh);
                    Cs8[row * LDC8 + col] = to_fp8(elu_f(acc[mi][ni][r] + bv));
                }
            }
        }
        __syncthreads();
        constexpr int C16 = COUT_B / 16;
#pragma unroll
        for (int j2 = tid; j2 < TILE_M * C16; j2 += 256) {
            int row = j2 / C16, c16 = j2 % C16;
            int gm = m0 + row;
            if (gm < NN)
                *(int4*)((unsigned char*)hout + (size_t)gm * COUT_TOT + col0 + c16 * 16)
                    = *(int4*)&Cs8[row * LDC8 + c16 * 16];
        }
    } else {
        __bf16* Cs = (__bf16*)smem;
        constexpr int LDC = COUT_B + 8;
#pragma unroll
        for (int ni = 0; ni < NT; ++ni) {
            const int col = wc * WN + ni * 32 + ml;
            const float bv = bias[col0 + col];
#pragma unroll
            for (int mi = 0; mi < MT; ++mi) {
#pragma unroll
                for (int r = 0; r < 16; ++r) {
                    int row = wr * WM + mi * 32 + ((r & 3) + 8 * (r >> 2) + 4 * kh);
                    Cs[row * LDC + col] = (__bf16)elu_f(acc[mi][ni][r] + bv);
                }
            }
        }
        __syncthreads();
        constexpr int C8 = COUT_B / 8;
#pragma unroll
        for (int j2 = tid; j2 < TILE_M * C8; j2 += 256) {
            int row = j2 / C8, c8 = j2 % C8;
            int gm = m0 + row;
            if (gm < NN)
                *(int4*)&((__bf16*)hout)[(size_t)gm * COUT_TOT + col0 + c8 * 8] = *(int4*)&Cs[row * LDC + c8 * 8];
        }
    }
}

// ------------------------------------------- spiral3 MIXED + FUSED fc1/fc2/log_softmax
// K-loop: EXACT R20/R22-green kernel (TILE 64, RW=2/CW=2, wave 32x64, K=1024,
// NSTEP=16, depth-2 NBUFS=3, wait-at-top, R20 NW formula) -- DO NOT TOUCH.
// Fused tail (R26): acc -> LDS in fc1 A-layout, then the R25-proven fc12 body per
// 32-row half. R27: P-reduction buffer ALIASED onto Cs2 (never simultaneously
// live; existing barriers separate them). LDS map: loop A-ring [0,24576) -- dead
// after final sync. Tail: h3A [0,8192) h3B [8192,16384) Cs2+P [16384,33280).
__global__ __launch_bounds__(256, 2) void mfma3_fused(const unsigned char* __restrict__ h2f8, // [N,64] e4m3
                                                      const int* __restrict__ idxT,
                                                      const __bf16* __restrict__ Wsw,   // w3 frag-major (K=1024,C=128)
                                                      const float* __restrict__ bias3,
                                                      const __bf16* __restrict__ Wf1,   // fc1 frag-major (K=128,C=256)
                                                      const float* __restrict__ bias1,
                                                      const __bf16* __restrict__ W2p,   // fc2 frag-major padded (K=256,C=32)
                                                      const float* __restrict__ bias2,
                                                      float* __restrict__ out)
{
    constexpr int NN = 100000;
    constexpr int NSTEP = 16;
    constexpr int D = 2;        // DMA insts per step per wave (32 rows x 64 B)
    constexpr int Bn = 8;       // B vmem loads per step
    constexpr int I = 2;        // idx loads per step
    constexpr int NBUFS = 3;
    __shared__ __align__(16) char smem[33280];

    const int tid = threadIdx.x;
    const int lane = tid & 63;
    const int w = tid >> 6;
    const int wr = w >> 1;
    const int wc = w & 1;
    const int ml = lane & 31;
    const int kh = lane >> 5;
    const int m0 = blockIdx.x * 64;
    const int rbase = m0 + wr * 32;

    char* const Aw = smem + w * (NBUFS * 2048);

    // DMA geometry: inst i, lane t -> row r=i*16+(t>>2), phys chunk t&3 holds src chunk
    // (t&3) ^ (r&3) ^ ((r>>2)&3)
    int ioff[D], koff[D];
#pragma unroll
    for (int i = 0; i < D; ++i) {
        int r = i * 16 + (lane >> 2);
        int c = (lane & 3) ^ (r & 3) ^ ((r >> 2) & 3);
        int gm = rbase + r; if (gm >= NN) gm = NN - 1;
        ioff[i] = gm;
        koff[i] = c * 16;
    }

    bf16x8 bfr[2][2][4];
    int myIdx[3][D];

    const __bf16* wlane = Wsw + ((size_t)(wc * 64 + ml) + (size_t)kh * 128) * 8;

    auto loadB = [&](auto sc) {
        constexpr int s = decltype(sc)::value;
        if constexpr (s < NSTEP) {
#pragma unroll
            for (int ni = 0; ni < 2; ++ni)
#pragma unroll
                for (int ks = 0; ks < 4; ++ks)
                    bfr[s & 1][ni][ks] = *(const bf16x8*)(wlane
                        + (size_t)(s * 8 + ks * 2) * 128 * 8 + ni * 32 * 8);
        }
    };
    auto loadIdxS = [&](auto sc) {
        constexpr int s = decltype(sc)::value;
        if constexpr (s < NSTEP) {
#pragma unroll
            for (int i = 0; i < D; ++i)
                myIdx[s % 3][i] = idxT[(size_t)s * NN + ioff[i]];
        }
    };
    auto issueDMA = [&](auto sc) {
        constexpr int s = decltype(sc)::value;
        if constexpr (s < NSTEP) {
            char* base = Aw + (s % NBUFS) * 2048;
#pragma unroll
            for (int i = 0; i < D; ++i) {
                const unsigned char* src = h2f8 + (size_t)myIdx[s % 3][i] * 64 + koff[i];
                __builtin_amdgcn_global_load_lds(
                    (const __attribute__((address_space(1))) void*)src,
                    (__attribute__((address_space(3))) void*)(base + i * 1024),
                    16, 0, 0);
            }
        }
    };

    f32x16 acc[2];
    { f32x16 z = {}; acc[0] = z; acc[1] = z; }

    // depth-2 prologue: idx0..2, B0, DMA0, DMA1, idx3
    loadIdxS(ic<0>{});
    loadIdxS(ic<1>{});
    loadIdxS(ic<2>{});
    memfence_sched();
    loadB(ic<0>{});
    memfence_sched();
    issueDMA(ic<0>{});
    memfence_sched();
    issueDMA(ic<1>{});
    memfence_sched();
    loadIdxS(ic<3>{});
    memfence_sched();

    static_for<NSTEP>([&](auto sc) {
        constexpr int s = decltype(sc)::value;
        // wait for DMA(s) at iteration TOP. Ops issued after DMA(s):
        //  s==0 (prologue): DMA(1)=D, idx(3)=I.
        //  s>=1: idx(s+2) [iter s-2] + B(s) [iter s-1, always] + DMA(s+1) + idx(s+3).
        constexpr int NW = (s == 0)
            ? (D * (1 < NSTEP) + I * (3 < NSTEP))
            : (I * (s + 2 < NSTEP) + Bn + D * (s + 1 < NSTEP) + I * (s + 3 < NSTEP));
        wait_vmcnt<NW>();
        memfence_sched();

        // ds_read raw fp8 rows (pinned between fences: cannot move above the wait)
        const char* base = Aw + (s % NBUFS) * 2048;
        long a8[4];
#pragma unroll
        for (int ks = 0; ks < 4; ++ks)
            a8[ks] = *(const long*)(base + ml * 64
                + (((ks ^ (ml & 3)) ^ ((ml >> 2) & 3)) << 4) + kh * 8);
        memfence_sched();

        // issue next-iteration vmem while this iteration computes
        loadB(ic<s + 1>{});
        memfence_sched();
        issueDMA(ic<s + 2>{});
        memfence_sched();
        loadIdxS(ic<s + 4>{});
        memfence_sched();

        bf16x8 afr[4];
#pragma unroll
        for (int ks = 0; ks < 4; ++ks)
            afr[ks] = dq8(a8[ks]);   // HW fp8 e4m3 -> bf16 (exact)
#pragma unroll
        for (int ks = 0; ks < 4; ++ks)
#pragma unroll
            for (int ni = 0; ni < 2; ++ni)
                acc[ni] = __builtin_amdgcn_mfma_f32_32x32x16_bf16(
                    afr[ks], bfr[s & 1][ni][ks], acc[ni], 0, 0, 0);
    });

    // ---- fused tail: h3-tile -> LDS in fc1 A-layout, then fc1+fc2+log_softmax
    __syncthreads();
    {
        // wave (wr,wc) computed h3 rows wr*32+crow(r), cols wc*64+ni*32+ml.
        // fc1-A layout byte (r16 in [0,32), k in [0,128)):
        //   r16*256 + ((k>>3) ^ (r16&15))*16 + (k&7)*2, half base = wr*8192.
        char* Ah = smem + wr * 8192;
#pragma unroll
        for (int ni = 0; ni < 2; ++ni) {
            const int col = wc * 64 + ni * 32 + ml;
            const float bv = bias3[col];
#pragma unroll
            for (int r = 0; r < 16; ++r) {
                int r16 = (r & 3) + 8 * (r >> 2) + 4 * kh;
                *(__bf16*)(Ah + r16 * 256 + (((col >> 3) ^ (r16 & 15)) << 4) + (col & 7) * 2)
                    = (__bf16)elu_f(acc[ni][r] + bv);
            }
        }
    }
    __syncthreads();

    // fc2 B fragments (loaded once; cannot migrate into the K-loop -- post-loop code)
    bf16x8 b2f[4];
#pragma unroll
    for (int ks = 0; ks < 4; ++ks)
        b2f[ks] = *(const bf16x8*)&W2p[((w * 8 + ks * 2 + kh) * 32 + ml) * 8];

    const __bf16* wlane1 = Wf1 + ((size_t)(w * 64 + ml) + (size_t)kh * 256) * 8;
    __bf16* Cs2 = (__bf16*)(smem + 16384);
    char* Pbase = smem + 16384;   // ALIASED onto Cs2 (never simultaneously live)

#pragma unroll
    for (int half = 0; half < 2; ++half) {
        const char* Ab = smem + half * 8192;

        f32x16 acc1[2];
        { f32x16 z = {}; acc1[0] = z; acc1[1] = z; }
#pragma unroll
        for (int s = 0; s < 2; ++s) {
            bf16x8 afr1[4];
#pragma unroll
            for (int ks = 0; ks < 4; ++ks) {
                int c16 = s * 8 + ks * 2 + kh;
                afr1[ks] = *(const bf16x8*)(Ab + ml * 256 + ((c16 ^ (ml & 15)) * 16));
            }
            bf16x8 bfr1[2][4];
#pragma unroll
            for (int ni = 0; ni < 2; ++ni)
#pragma unroll
                for (int ks = 0; ks < 4; ++ks)
                    bfr1[ni][ks] = *(const bf16x8*)(wlane1
                        + (size_t)(s * 8 + ks * 2) * 256 * 8 + ni * 32 * 8);
#pragma unroll
            for (int ks = 0; ks < 4; ++ks)
#pragma unroll
                for (int ni = 0; ni < 2; ++ni)
                    acc1[ni] = __builtin_amdgcn_mfma_f32_32x32x16_bf16(
                        afr1[ks], bfr1[ni][ks], acc1[ni], 0, 0, 0);
        }
        __syncthreads();   // protect Cs2/P region from previous half's readers

#pragma unroll
        for (int ni = 0; ni < 2; ++ni) {
            int col = w * 64 + ni * 32 + ml;
            float bv = bias1[col];
#pragma unroll
            for (int r = 0; r < 16; ++r) {
                int row = (r & 3) + 8 * (r >> 2) + 4 * kh;
                Cs2[row * 264 + col] = (__bf16)elu_f(acc1[ni][r] + bv);
            }
        }
        __syncthreads();

        bf16x8 a2[4];
#pragma unroll
        for (int ks = 0; ks < 4; ++ks)
            a2[ks] = *(const bf16x8*)&Cs2[ml * 264 + w * 64 + ks * 16 + kh * 8];
        f32x16 acc2;
        { f32x16 z = {}; acc2 = z; }
#pragma unroll
        for (int ks = 0; ks < 4; ++ks)
            acc2 = __builtin_amdgcn_mfma_f32_32x32x16_bf16(a2[ks], b2f[ks], acc2, 0, 0, 0);
        __syncthreads();   // all a2 reads done -> safe to overwrite Cs2 region with P

        float* P = (float*)(Pbase + w * 4096);
#pragma unroll
        for (int r = 0; r < 16; ++r)
            P[((r & 3) + 8 * (r >> 2) + 4 * kh) * 32 + ml] = acc2[r];
        __syncthreads();

        float4 s4 = make_float4(0.f, 0.f, 0.f, 0.f);
#pragma unroll
        for (int pw = 0; pw < 4; ++pw) {
            float4 v = *(float4*)(Pbase + pw * 4096 + tid * 16);
            s4.x += v.x; s4.y += v.y; s4.z += v.z; s4.w += v.w;
        }
        __syncthreads();
        *(float4*)(Pbase + tid * 16) = s4;
        __syncthreads();

        if (tid < 32) {
            int n = m0 + half * 32 + tid;
            if (n < NN) {
                const float* L = (float*)Pbase + tid * 32;
                float logits[12], mx = -1e30f;
#pragma unroll
                for (int o = 0; o < 12; ++o) {
                    logits[o] = L[o] + bias2[o];
                    mx = fmaxf(mx, logits[o]);
                }
                float s = 0.f;
#pragma unroll
                for (int o = 0; o < 12; ++o) s += expf(logits[o] - mx);
                float lse = mx + logf(s);
                float4 o0 = make_float4(logits[0] - lse, logits[1] - lse, logits[2] - lse, logits[3] - lse);
                float4 o1 = make_float4(logits[4] - lse, logits[5] - lse, logits[6] - lse, logits[7] - lse);
                float4 o2 = make_float4(logits[8] - lse, logits[9] - lse, logits[10] - lse, logits[11] - lse);
                *(float4*)&out[(size_t)n * 12 + 0] = o0;
                *(float4*)&out[(size_t)n * 12 + 4] = o1;
                *(float4*)&out[(size_t)n * 12 + 8] = o2;
            }
        }
    }
}

extern "C" void kernel_launch(void* const* d_in, const int* in_sizes, int n_in,
                              void* d_out, int out_size, void* d_ws, size_t ws_size,
                              hipStream_t stream)
{
    const int N = 100000;
    const float* x     = (const float*)d_in[0];
    const int*   idx   = (const int*)  d_in[1];
    const float* fc0_w = (const float*)d_in[2];
    const float* fc0_b = (const float*)d_in[3];
    const float* w1    = (const float*)d_in[4];
    const float* b1    = (const float*)d_in[5];
    const float* w2    = (const float*)d_in[6];
    const float* b2    = (const float*)d_in[7];
    const float* w3    = (const float*)d_in[8];
    const float* b3    = (const float*)d_in[9];
    const float* fc1_w = (const float*)d_in[10];
    const float* fc1_b = (const float*)d_in[11];
    const float* fc2_w = (const float*)d_in[12];
    const float* fc2_b = (const float*)d_in[13];
    float* out = (float*)d_out;

    // ---- workspace layout
    char* ws = (char*)d_ws;
    const int n_w1 = 32 * 256, n_w2 = 64 * 512, n_w3 = 128 * 1024, n_fc1 = 256 * 128;
    const int n_fc2p = 32 * 256;
    const int n_wb = n_w1 + n_w2 + n_w3 + n_fc1 + n_fc2p;   // 212992
    __bf16* w1b = (__bf16*)ws;
    __bf16* w2b = w1b + n_w1;
    __bf16* w3b = w2b + n_w2;
    __bf16* f1b = w3b + n_w3;
    __bf16* f2b = f1b + n_fc1;
    size_t off = ((size_t)n_wb * 2 + 4095) & ~(size_t)4095;
    int* idxT = (int*)(ws + off);              off += (size_t)N * 16 * 4;
    __bf16* h0 = (__bf16*)(ws + off);          off += (size_t)N * 16 * 2;
    __bf16* h1 = (__bf16*)(ws + off);          off += (size_t)N * 32 * 2;
    unsigned char* h2f8 = (unsigned char*)(ws + off);  off += (size_t)N * 64;

    // FUSED prep: weight swizzle (832) + idxT LDS-transpose (391) + fc0 (391).
    prep_kernel<<<1614, 256, 0, stream>>>(w1, w2, w3, fc1_w, fc2_w,
                                          w1b, w2b, w3b, f1b, f2b,
                                          idx, idxT, x, fc0_w, fc0_b, h0, N);

    // spiral1: 16ch x16 -> 32 bf16. TILE 128 (RW=4, CW=1), NSTEP=4, depth-2 hardened.
    mfma_layer<16, 16, 32, 32, 128, 4, 1, true, false, 3, 100000>
        <<<dim3((N + 127) / 128, 1), 256, 0, stream>>>(h0, idxT, w1b, b1, (void*)h1);
    // spiral2: 32ch x16 -> 64, OUTPUT fp8 h2. TILE 128 (RW=4, CW=1), NSTEP=8, depth-2 hardened.
    mfma_layer<32, 16, 64, 64, 128, 4, 1, true, true, 3, 100000>
        <<<dim3((N + 127) / 128, 1), 256, 0, stream>>>(h1, idxT, w2b, b2, (void*)h2f8);
    // spiral3 MIXED + fused fc1/fc2/log_softmax (h3 never materialized).
    mfma3_fused<<<(N + 63) / 64, 256, 0, stream>>>(h2f8, idxT, w3b, b3,
                                                   f1b, fc1_b, f2b, fc2_b, out);
}